// Round 2
// baseline (288.986 us; speedup 1.0000x reference)
//
#include <hip/hip_runtime.h>
#include <stdint.h>

// out[b,s,u] = (LN(x) @ ternary(W)) * mean|W|   (reference's gamma absmax cancels)
// Fused pipeline: absum -> ternarize(W^T) -> [LN + per-row i8 quant + i8 GEMM] in ONE kernel.
// Removes the 66 MB xq HBM round-trip of the 4-kernel version.
// x: (4,8192,1024) fp32 -> M=32768, K=1024, N=1024, out fp32.

#define M_ROWS 32768
#define KDIM 1024
#define NDIM 1024

typedef int v4i  __attribute__((ext_vector_type(4)));
typedef int v16i __attribute__((ext_vector_type(16)));

// ---------------- kernel 1: |w| partial sums (no atomics, no memset) ------------
__global__ __launch_bounds__(256) void absum_k(const float* __restrict__ w,
                                               float* __restrict__ partials) {
    int idx = blockIdx.x * 256 + threadIdx.x;
    float4 v = ((const float4*)w)[idx];
    float s = fabsf(v.x) + fabsf(v.y) + fabsf(v.z) + fabsf(v.w);
    #pragma unroll
    for (int o = 32; o; o >>= 1) s += __shfl_xor(s, o);
    __shared__ float p[4];
    if ((threadIdx.x & 63) == 0) p[threadIdx.x >> 6] = s;
    __syncthreads();
    if (threadIdx.x == 0) partials[blockIdx.x] = p[0] + p[1] + p[2] + p[3];
}

// ---------------- kernel 2: ternarize + transpose -> wqT[n][k] i8 ---------------
__global__ __launch_bounds__(256) void quant_k(const float* __restrict__ w,
                                               const float* __restrict__ partials,
                                               char* __restrict__ wqT,
                                               float* __restrict__ wsum) {
    int t = threadIdx.x;
    float s = partials[t] + partials[t + 256] + partials[t + 512] + partials[t + 768];
    #pragma unroll
    for (int o = 32; o; o >>= 1) s += __shfl_xor(s, o);
    __shared__ float ps[4];
    if ((t & 63) == 0) ps[t >> 6] = s;
    __syncthreads();
    float total = ps[0] + ps[1] + ps[2] + ps[3];
    if (blockIdx.x == 0 && t == 0) wsum[0] = total;
    float beta = total * (1.0f / 1048576.0f);
    float inv  = 1.0f / (beta + 1e-5f);

    __shared__ char sT[64 * 80];           // [n][k], stride 80 (16B-aligned rows)
    int k0 = (blockIdx.x >> 4) * 64, n0 = (blockIdx.x & 15) * 64;
    int n_l = t & 63;
    #pragma unroll
    for (int r = 0; r < 16; ++r) {
        int k_l = (t >> 6) * 16 + r;
        float q = rintf(w[(size_t)(k0 + k_l) * NDIM + n0 + n_l] * inv);
        q = fminf(1.0f, fmaxf(-1.0f, q));
        sT[n_l * 80 + k_l] = (char)(int)q;
    }
    __syncthreads();
    int nn = t >> 2, c = t & 3;
    v4i val = *(const v4i*)&sT[nn * 80 + c * 16];
    *(v4i*)&wqT[(size_t)(n0 + nn) * KDIM + k0 + c * 16] = val;
}

// ---------------- kernel 3: fused LN + per-row i8 quant + i8 GEMM ---------------
// Block: 256 threads (4 waves), BM=64 rows, full N=1024.
// LDS: sA 64x1024 i8 (16B-chunk XOR swizzle by row&7) + sB 8 KB single-buffer B tile
//      ([n-pair][128B] rows, 8-slot XOR swizzle) + 64 row scales = 74 KB -> 2 blocks/CU.
// Phase 1: wave LNs 16 rows in-register, quantizes into sA. Phase 2: B tiles
// (n0 in 0..7, kt in 0..15, BK=64) reg-prefetched depth-2 into sB; per-n0 epilogue
// interleaves the 134 MB out-write with compute. acc i32 exact; scales in epilogue.
__global__ __launch_bounds__(256) void ln_gemm_k(const float* __restrict__ x,
                                                 const float* __restrict__ g,
                                                 const float* __restrict__ bln,
                                                 const char* __restrict__ wq,
                                                 const float* __restrict__ wsum,
                                                 float* __restrict__ out) {
    __shared__ char  sA[64 * 1024];
    __shared__ char  sB[64 * 128];
    __shared__ float sScl[64];

    int t = threadIdx.x;
    int w = t >> 6, lane = t & 63;
    int half = lane >> 5, l31 = lane & 31;
    int bm0 = blockIdx.x * 64;

    // B-staging lane geometry: thread t loads 32B of row n=t>>1 (full 64B L2 line per pair)
    int bn_l  = t >> 1;              // n within current 128-row tile
    int bhalf = t & 1;               // which 32B half of the 64B k-slice
    int br    = t >> 2;              // sB row (n-pair), 128 B each

    v4i buf[2];
    {   // prefetch tile 0 (n0=0, kt=0) into regs — overlaps with phase 1 below
        const char* src = wq + ((size_t)bn_l << 10) + bhalf * 32;
        buf[0] = *(const v4i*)(src);
        buf[1] = *(const v4i*)(src + 16);
    }

    // ---- phase 1: LN + per-row quant into sA ----
    // gamma/beta columns for this lane are fixed across rows: preload once.
    float4 g4[4], b4[4];
    #pragma unroll
    for (int j = 0; j < 4; ++j) {
        g4[j] = ((const float4*)g)[lane + 64 * j];
        b4[j] = ((const float4*)bln)[lane + 64 * j];
    }
    #pragma unroll 1
    for (int rr = 0; rr < 16; ++rr) {
        int row = w * 16 + rr;
        const float4* xr = (const float4*)(x + ((size_t)(bm0 + row) << 10));
        float4 v0 = xr[lane], v1 = xr[lane + 64], v2 = xr[lane + 128], v3 = xr[lane + 192];
        float s  = v0.x + v0.y + v0.z + v0.w + v1.x + v1.y + v1.z + v1.w
                 + v2.x + v2.y + v2.z + v2.w + v3.x + v3.y + v3.z + v3.w;
        float ss = v0.x*v0.x + v0.y*v0.y + v0.z*v0.z + v0.w*v0.w
                 + v1.x*v1.x + v1.y*v1.y + v1.z*v1.z + v1.w*v1.w
                 + v2.x*v2.x + v2.y*v2.y + v2.z*v2.z + v2.w*v2.w
                 + v3.x*v3.x + v3.y*v3.y + v3.z*v3.z + v3.w*v3.w;
        #pragma unroll
        for (int o = 32; o; o >>= 1) { s += __shfl_xor(s, o); ss += __shfl_xor(ss, o); }
        float mu  = s * (1.0f / 1024.0f);
        float var = ss * (1.0f / 1024.0f) - mu * mu;
        float rs  = rsqrtf(var + 1e-3f);        // keras LN eps
        float xn[16];
        float4 vv[4] = {v0, v1, v2, v3};
        float mx = 0.f;
        #pragma unroll
        for (int j = 0; j < 4; ++j) {
            xn[4*j+0] = (vv[j].x - mu) * rs * g4[j].x + b4[j].x;
            xn[4*j+1] = (vv[j].y - mu) * rs * g4[j].y + b4[j].y;
            xn[4*j+2] = (vv[j].z - mu) * rs * g4[j].z + b4[j].z;
            xn[4*j+3] = (vv[j].w - mu) * rs * g4[j].w + b4[j].w;
            #pragma unroll
            for (int e = 0; e < 4; ++e) mx = fmaxf(mx, fabsf(xn[4*j+e]));
        }
        #pragma unroll
        for (int o = 32; o; o >>= 1) mx = fmaxf(mx, __shfl_xor(mx, o));
        mx = fmaxf(mx, 1e-20f);
        float inv = 127.0f / mx;
        if (lane == 0) sScl[row] = mx * (1.0f / 127.0f);
        #pragma unroll
        for (int j = 0; j < 4; ++j) {
            char4 c4;
            c4.x = (char)(int)rintf(xn[4*j+0] * inv);
            c4.y = (char)(int)rintf(xn[4*j+1] * inv);
            c4.z = (char)(int)rintf(xn[4*j+2] * inv);
            c4.w = (char)(int)rintf(xn[4*j+3] * inv);
            int c    = (lane >> 2) + 16 * j;          // 16B chunk index in the 1KB row
            int slot = c ^ (row & 7);                 // XOR swizzle (matches MFMA read)
            *(char4*)&sA[row * 1024 + slot * 16 + (lane & 3) * 4] = c4;
        }
    }

    {   // stage tile 0 into sB, prefetch tile 1 (n0=0, kt=1)
        #pragma unroll
        for (int q = 0; q < 2; ++q) {
            int slot = (((bn_l & 1) * 4 + bhalf * 2 + q) ^ (br & 7));
            *(v4i*)&sB[br * 128 + slot * 16] = buf[q];
        }
        const char* src = wq + ((size_t)bn_l << 10) + 64 + bhalf * 32;
        buf[0] = *(const v4i*)(src);
        buf[1] = *(const v4i*)(src + 16);
    }
    __syncthreads();   // sA, sScl, sB(tile0) all visible

    // ---- phase 2: GEMM. Waves 2m x 2n; wave owns 32m x 64n per n0-tile. ----
    int wm = w & 1, wn = w >> 1;
    int mrow  = wm * 32 + l31;
    int aBase = mrow * 1024;
    int am7   = mrow & 7;
    int nl0 = wn * 64 + l31;
    int br0 = nl0 >> 1, br1 = (nl0 + 32) >> 1;
    int bs0 = (nl0 & 1) * 4;                     // nl0+32 keeps the same &1
    float beta = wsum[0] * (1.0f / 1048576.0f);

    v16i acc[2];
    #pragma unroll
    for (int r = 0; r < 16; ++r) { acc[0][r] = 0; acc[1][r] = 0; }

    for (int it = 0; it < 128; ++it) {           // it = n0*16 + kt
        int kt = it & 15;
        #pragma unroll
        for (int kk = 0; kk < 2; ++kk) {
            int cA = kt * 4 + kk * 2 + half;     // k-run = kt*64 + kk*32 + half*16
            v4i a  = *(const v4i*)&sA[aBase + ((cA ^ am7) << 4)];
            int ct = kk * 2 + half;
            v4i b0 = *(const v4i*)&sB[br0 * 128 + (((bs0 + ct) ^ (br0 & 7)) << 4)];
            v4i b1 = *(const v4i*)&sB[br1 * 128 + (((bs0 + ct) ^ (br1 & 7)) << 4)];
            acc[0] = __builtin_amdgcn_mfma_i32_32x32x32_i8(a, b0, acc[0], 0, 0, 0);
            acc[1] = __builtin_amdgcn_mfma_i32_32x32x32_i8(a, b1, acc[1], 0, 0, 0);
        }
        __syncthreads();                          // all waves done reading sB(it)
        if (it < 127) {                           // write tile it+1 (held in regs)
            #pragma unroll
            for (int q = 0; q < 2; ++q) {
                int slot = (((bn_l & 1) * 4 + bhalf * 2 + q) ^ (br & 7));
                *(v4i*)&sB[br * 128 + slot * 16] = buf[q];
            }
        }
        if (it < 126) {                           // prefetch tile it+2 into regs
            int tl = it + 2;
            const char* src = wq + ((size_t)(((tl >> 4) << 7) + bn_l) << 10)
                                 + (tl & 15) * 64 + bhalf * 32;
            buf[0] = *(const v4i*)(src);
            buf[1] = *(const v4i*)(src + 16);
        }
        if (kt == 15) {                           // per-n0 epilogue: overlap out-writes
            int n0 = it >> 4;
            int colBase = n0 * 128 + wn * 64 + l31;
            #pragma unroll
            for (int r = 0; r < 16; ++r) {
                // C/D 32x32: col = lane&31, row = (r&3) + 8*(r>>2) + 4*(lane>>5)
                int rloc = wm * 32 + (r & 3) + 8 * (r >> 2) + 4 * half;
                float sc = sScl[rloc] * beta;
                size_t o = (size_t)(bm0 + rloc) * NDIM + colBase;
                out[o]      = (float)acc[0][r] * sc;
                out[o + 32] = (float)acc[1][r] * sc;
            }
            #pragma unroll
            for (int r = 0; r < 16; ++r) { acc[0][r] = 0; acc[1][r] = 0; }
        }
        __syncthreads();                          // sB(it+1) ready
    }
}

extern "C" void kernel_launch(void* const* d_in, const int* in_sizes, int n_in,
                              void* d_out, int out_size, void* d_ws, size_t ws_size,
                              hipStream_t stream) {
    const float* x        = (const float*)d_in[0];   // 4*8192*1024
    const float* weight   = (const float*)d_in[1];   // 1024*1024
    const float* ln_gamma = (const float*)d_in[2];   // 1024
    const float* ln_beta  = (const float*)d_in[3];   // 1024
    float* out = (float*)d_out;

    // ws layout: [0,4) wsum | [4K, 8K) partials(1024 f32) | [256K, 256K+1M) wqT i8
    float* wsum     = (float*)d_ws;
    float* partials = (float*)((char*)d_ws + 4096);
    char*  wqT      = (char*)d_ws + (1u << 18);

    absum_k<<<1024, 256, 0, stream>>>(weight, partials);
    quant_k<<<256, 256, 0, stream>>>(weight, partials, wqT, wsum);
    ln_gemm_k<<<M_ROWS / 64, 256, 0, stream>>>(x, ln_gamma, ln_beta, wqT, wsum, out);
}

// Round 3
// 283.906 us; speedup vs baseline: 1.0179x; 1.0179x over previous
//
#include <hip/hip_runtime.h>
#include <stdint.h>

// out[b,s,u] = (LN(x) @ ternary(W)) * mean|W|   (reference's gamma absmax cancels)
// Fused: absum -> ternarize into MFMA-frag-packed wqP -> [LN + i8 quant + barrier-free GEMM].
// Phase 2 has ZERO barriers: B frags stream straight from L2 (wqP packed 1KB/frag),
// A frags from a frag-major conflict-free LDS layout. x: (4,8192,1024) fp32.
// M=32768, K=1024, N=1024, out fp32.

#define M_ROWS 32768
#define KDIM 1024
#define NDIM 1024

typedef int v4i  __attribute__((ext_vector_type(4)));
typedef int v16i __attribute__((ext_vector_type(16)));

// ---------------- kernel 1: |w| partial sums (no atomics, no memset) ------------
__global__ __launch_bounds__(256) void absum_k(const float* __restrict__ w,
                                               float* __restrict__ partials) {
    int idx = blockIdx.x * 256 + threadIdx.x;
    float4 v = ((const float4*)w)[idx];
    float s = fabsf(v.x) + fabsf(v.y) + fabsf(v.z) + fabsf(v.w);
    #pragma unroll
    for (int o = 32; o; o >>= 1) s += __shfl_xor(s, o);
    __shared__ float p[4];
    if ((threadIdx.x & 63) == 0) p[threadIdx.x >> 6] = s;
    __syncthreads();
    if (threadIdx.x == 0) partials[blockIdx.x] = p[0] + p[1] + p[2] + p[3];
}

// ------- kernel 2: ternarize -> wqP packed MFMA-frag-major ----------------------
// Frag (nb, s) = B[n=nb*32+l31][k=s*32+(l>>5)*16 .. +16] for lane l, stored as
// 64 contiguous 16B units at wqP[((nb*32+s)*64 + l)*16]. One wave-load = 1KB linear.
__global__ __launch_bounds__(256) void quant_k(const float* __restrict__ w,
                                               const float* __restrict__ partials,
                                               char* __restrict__ wqP,
                                               float* __restrict__ wsum) {
    int t = threadIdx.x;
    float s = partials[t] + partials[t + 256] + partials[t + 512] + partials[t + 768];
    #pragma unroll
    for (int o = 32; o; o >>= 1) s += __shfl_xor(s, o);
    __shared__ float ps[4];
    if ((t & 63) == 0) ps[t >> 6] = s;
    __syncthreads();
    float total = ps[0] + ps[1] + ps[2] + ps[3];
    if (blockIdx.x == 0 && t == 0) wsum[0] = total;
    float beta = total * (1.0f / 1048576.0f);
    float inv  = 1.0f / (beta + 1e-5f);

    __shared__ char sT[64 * 80];           // [n][k], stride 80 (16B-aligned rows)
    int k0 = (blockIdx.x >> 4) * 64, n0 = (blockIdx.x & 15) * 64;
    int n_l = t & 63;
    #pragma unroll
    for (int r = 0; r < 16; ++r) {
        int k_l = (t >> 6) * 16 + r;
        float q = rintf(w[(size_t)(k0 + k_l) * NDIM + n0 + n_l] * inv);
        q = fminf(1.0f, fmaxf(-1.0f, q));
        sT[n_l * 80 + k_l] = (char)(int)q;
    }
    __syncthreads();
    int nn = t >> 2, c = t & 3;
    v4i val = *(const v4i*)&sT[nn * 80 + c * 16];
    int n = n0 + nn, k = k0 + c * 16;
    int idx = ((n >> 5) * 32 + (k >> 5)) * 64 + (n & 31) + ((k >> 4) & 1) * 32;
    *(v4i*)&wqP[(size_t)idx * 16] = val;
}

// ---------------- kernel 3: fused LN + i8 quant + barrier-free i8 GEMM ----------
// 256 thr (4 waves), BM=64 rows, full N=1024. LDS = sA 64KB frag-major + scales.
// sA unit U = mf*64 + u (u = k/16), 32 slots x 16B; slot = (row&31) ^ (u&7):
// per-row ds_write_b128 and per-frag ds_read_b128 are both minimum-cycle.
// Phase 2: ONE barrier total. Each wave: 64m x 128n, K streamed s=0..31,
// A depth-2 from LDS, B depth-2 from L2 (packed 1KB frags), 8 MFMA/step.
// 2 n-passes (512 cols each) with per-pass epilogue (out-writes overlap pass 1).
__global__ __launch_bounds__(256, 2) void ln_gemm_k(const float* __restrict__ x,
                                                    const float* __restrict__ g,
                                                    const float* __restrict__ bln,
                                                    const char* __restrict__ wqP,
                                                    const float* __restrict__ wsum,
                                                    float* __restrict__ out) {
    __shared__ char  sA[64 * 1024];
    __shared__ float sScl[64];

    int t = threadIdx.x;
    int w = t >> 6, lane = t & 63;
    int half = lane >> 5, l31 = lane & 31;
    int bm0 = blockIdx.x * 64;

    // ---- phase 1: LN + per-row quant into frag-major sA ----
    // Lane owns k = lane*16 .. +16 (16 consecutive elements) => one 16B unit/row.
    float4 g4[4], b4[4];
    #pragma unroll
    for (int j = 0; j < 4; ++j) {
        g4[j] = ((const float4*)g)[lane * 4 + j];
        b4[j] = ((const float4*)bln)[lane * 4 + j];
    }
    #pragma unroll 1
    for (int rr = 0; rr < 16; ++rr) {
        int row = w * 16 + rr;
        const float4* xr = (const float4*)(x + ((size_t)(bm0 + row) << 10));
        float4 v0 = xr[lane * 4], v1 = xr[lane * 4 + 1], v2 = xr[lane * 4 + 2], v3 = xr[lane * 4 + 3];
        float s  = v0.x + v0.y + v0.z + v0.w + v1.x + v1.y + v1.z + v1.w
                 + v2.x + v2.y + v2.z + v2.w + v3.x + v3.y + v3.z + v3.w;
        float ss = v0.x*v0.x + v0.y*v0.y + v0.z*v0.z + v0.w*v0.w
                 + v1.x*v1.x + v1.y*v1.y + v1.z*v1.z + v1.w*v1.w
                 + v2.x*v2.x + v2.y*v2.y + v2.z*v2.z + v2.w*v2.w
                 + v3.x*v3.x + v3.y*v3.y + v3.z*v3.z + v3.w*v3.w;
        #pragma unroll
        for (int o = 32; o; o >>= 1) { s += __shfl_xor(s, o); ss += __shfl_xor(ss, o); }
        float mu  = s * (1.0f / 1024.0f);
        float var = ss * (1.0f / 1024.0f) - mu * mu;
        float rs  = rsqrtf(var + 1e-3f);        // keras LN eps
        float xn[16];
        float4 vv[4] = {v0, v1, v2, v3};
        float mx = 0.f;
        #pragma unroll
        for (int j = 0; j < 4; ++j) {
            xn[4*j+0] = (vv[j].x - mu) * rs * g4[j].x + b4[j].x;
            xn[4*j+1] = (vv[j].y - mu) * rs * g4[j].y + b4[j].y;
            xn[4*j+2] = (vv[j].z - mu) * rs * g4[j].z + b4[j].z;
            xn[4*j+3] = (vv[j].w - mu) * rs * g4[j].w + b4[j].w;
            #pragma unroll
            for (int e = 0; e < 4; ++e) mx = fmaxf(mx, fabsf(xn[4*j+e]));
        }
        #pragma unroll
        for (int o = 32; o; o >>= 1) mx = fmaxf(mx, __shfl_xor(mx, o));
        mx = fmaxf(mx, 1e-20f);
        float inv = 127.0f / mx;
        if (lane == 0) sScl[row] = mx * (1.0f / 127.0f);
        int qw[4];
        #pragma unroll
        for (int j = 0; j < 4; ++j) {
            int b0 = (int)rintf(xn[4*j+0] * inv) & 255;
            int b1 = (int)rintf(xn[4*j+1] * inv) & 255;
            int b2 = (int)rintf(xn[4*j+2] * inv) & 255;
            int b3 = (int)rintf(xn[4*j+3] * inv) & 255;
            qw[j] = b0 | (b1 << 8) | (b2 << 16) | (b3 << 24);
        }
        v4i qv; qv[0] = qw[0]; qv[1] = qw[1]; qv[2] = qw[2]; qv[3] = qw[3];
        int mf = row >> 5, r31 = row & 31;
        int slot = r31 ^ (lane & 7);
        *(v4i*)&sA[(((mf * 64 + lane) * 32) + slot) * 16] = qv;
    }
    __syncthreads();                              // the ONLY barrier

    // ---- phase 2: barrier-free GEMM. Wave w: 64m x 128n per pass, 2 passes. ----
    float beta = wsum[0] * (1.0f / 1048576.0f);
    const v4i* wp = (const v4i*)wqP;

    #pragma unroll 1
    for (int p = 0; p < 2; ++p) {
        int nbB = p * 16 + w * 4;
        v16i acc[2][4] = {};
        v4i a0[2], a1[2], b0[4], b1[4];

        // A frag (mf, s): unit u = 2s+half, slot = l31 ^ (u&7)
        #define LA(dst, S) do { \
            int u_ = 2 * (S) + half; \
            int o_ = ((u_ * 32) + (l31 ^ (u_ & 7))) * 16; \
            dst[0] = *(const v4i*)&sA[o_]; \
            dst[1] = *(const v4i*)&sA[o_ + 32768]; \
        } while (0)
        #define LB(dst, S) do { \
            _Pragma("unroll") \
            for (int j_ = 0; j_ < 4; ++j_) \
                dst[j_] = wp[(size_t)(((nbB + j_) * 32 + (S)) * 64) + lane]; \
        } while (0)

        LB(b0, 0); LB(b1, 1); LA(a0, 0); LA(a1, 1);
        #pragma unroll 1
        for (int s = 0; s < 32; s += 2) {
            #pragma unroll
            for (int mf = 0; mf < 2; ++mf)
                #pragma unroll
                for (int j = 0; j < 4; ++j)
                    acc[mf][j] = __builtin_amdgcn_mfma_i32_32x32x32_i8(a0[mf], b0[j], acc[mf][j], 0, 0, 0);
            if (s + 2 < 32) { LB(b0, s + 2); LA(a0, s + 2); }
            #pragma unroll
            for (int mf = 0; mf < 2; ++mf)
                #pragma unroll
                for (int j = 0; j < 4; ++j)
                    acc[mf][j] = __builtin_amdgcn_mfma_i32_32x32x32_i8(a1[mf], b1[j], acc[mf][j], 0, 0, 0);
            if (s + 3 < 32) { LB(b1, s + 3); LA(a1, s + 3); }
        }
        #undef LA
        #undef LB

        // per-pass epilogue: out-writes of pass 0 overlap compute of pass 1
        #pragma unroll
        for (int mf = 0; mf < 2; ++mf) {
            #pragma unroll
            for (int r = 0; r < 16; ++r) {
                // C/D 32x32: col = lane&31, row = (r&3) + 8*(r>>2) + 4*(lane>>5)
                int rloc = mf * 32 + (r & 3) + 8 * (r >> 2) + 4 * half;
                float sc = sScl[rloc] * beta;
                size_t o = (size_t)(bm0 + rloc) * NDIM + p * 512 + w * 128 + l31;
                out[o]      = (float)acc[0 + mf][0][r] * sc;
                out[o + 32] = (float)acc[0 + mf][1][r] * sc;
                out[o + 64] = (float)acc[0 + mf][2][r] * sc;
                out[o + 96] = (float)acc[0 + mf][3][r] * sc;
            }
        }
    }
}

extern "C" void kernel_launch(void* const* d_in, const int* in_sizes, int n_in,
                              void* d_out, int out_size, void* d_ws, size_t ws_size,
                              hipStream_t stream) {
    const float* x        = (const float*)d_in[0];   // 4*8192*1024
    const float* weight   = (const float*)d_in[1];   // 1024*1024
    const float* ln_gamma = (const float*)d_in[2];   // 1024
    const float* ln_beta  = (const float*)d_in[3];   // 1024
    float* out = (float*)d_out;

    // ws layout: [0,4) wsum | [4K, 8K) partials(1024 f32) | [256K, 256K+1M) wqP i8
    float* wsum     = (float*)d_ws;
    float* partials = (float*)((char*)d_ws + 4096);
    char*  wqP      = (char*)d_ws + (1u << 18);

    absum_k<<<1024, 256, 0, stream>>>(weight, partials);
    quant_k<<<256, 256, 0, stream>>>(weight, partials, wqP, wsum);
    ln_gemm_k<<<M_ROWS / 64, 256, 0, stream>>>(x, ln_gamma, ln_beta, wqP, wsum, out);
}